// Round 11
// baseline (167.085 us; speedup 1.0000x reference)
//
#include <hip/hip_runtime.h>
#include <hip/hip_cooperative_groups.h>

namespace cg = cooperative_groups;

// SplashEncoding, round 11 (r10 + NaN fix).
// Radius-sum + MFMA (r9 validated: absmax 0.031 vs thr 0.086) on a 10^3 grid.
// r10 NaN root cause: FtT staged only cols [0,T); MFMA B-reads touch cols up
// to nkch*64-1 -> uninitialized LDS (stale int data = bf16 NaN patterns);
// 0 x NaN = NaN in the accumulator. Fix: zero-fill FtT cols [T, MAXC).
// Also MAXC 416->384 (r7/r8-validated cap) and FTP=392 (rows stagger 4 banks
// -> 2-way conflicts = free; 36.3KB LDS -> 4 blocks/CU).
// Structure: coop prep (zero->count->scan->scatter, grid.sync; r6-proven) +
// k_splash with wave-private Wq (barrier-free chunk loop), FtT staged once,
// wsum via ones-column MFMA accumulator + __shfl.

typedef short bf16x8 __attribute__((ext_vector_type(8)));
typedef float f32x4  __attribute__((ext_vector_type(4)));

constexpr int   M_Q   = 32768;
constexpr int   N_G   = 10000;
constexpr float EPS   = 1e-8f;
constexpr int   GD    = 10;
constexpr int   NCELL = GD * GD * GD;   // 1000
constexpr int   MAXC  = 384;            // candidate cap (observed max ~340)
constexpr int   FTP   = 392;            // FtT col pad: 784B rows, 4-bank stagger
constexpr int   NPAD  = 10240;          // padded slot count for global FgT rows

// ---- d_ws layout (int units) ----
#define W_GCNT   0          // [1000]   (gcnt+qcnt contiguous for zeroing)
#define W_QCNT   1000       // [1000]
#define W_GSTART 2000       // [1000]
#define W_QSTART 3000       // [1000]
#define W_GCUR   4000       // [1000]
#define W_QCUR   5000       // [1000]
#define W_SORTQ  6000       // [32768]
#define W_SMI    38768      // float4[20000]: {mean.xyz,0},{a.xyz,0} per slot
#define W_SCRD   118768     // float4[32768]: sorted query coords
#define W_FGT    249840     // ushort[32][10240]: bf16 feats TRANSPOSED
// end 413680 ints = 1.65 MB

__device__ __forceinline__ int cell_of(float x, float y, float z) {
    int cx = min(max((int)(x * (float)GD), 0), GD - 1);
    int cy = min(max((int)(y * (float)GD), 0), GD - 1);
    int cz = min(max((int)(z * (float)GD), 0), GD - 1);
    return (cx * GD + cy) * GD + cz;
}

__device__ __forceinline__ ushort f2bf(float x) {   // RNE f32->bf16
    union { float f; unsigned u; } v; v.f = x;
    unsigned r = v.u + 0x7FFFu + ((v.u >> 16) & 1u);
    return (ushort)(r >> 16);
}

// ---- phase bodies (shared by coop kernel and fallback kernels) ----

__device__ __forceinline__ void phase_count(int gid,
                                            const float* __restrict__ coords,
                                            const float* __restrict__ means,
                                            int* __restrict__ W) {
    if (gid < N_G)
        atomicAdd(W + W_GCNT + cell_of(means[gid*3+0], means[gid*3+1], means[gid*3+2]), 1);
    if (gid < M_Q)
        atomicAdd(W + W_QCNT + cell_of(coords[gid*3+0], coords[gid*3+1], coords[gid*3+2]), 1);
}

__device__ __forceinline__ void phase_scan(int bid, int tid, int* wp,
                                           int* __restrict__ W) {
    if (bid < 2) {
        const int* cnt = W + (bid ? W_QCNT   : W_GCNT);
        int*       st  = W + (bid ? W_QSTART : W_GSTART);
        int*       cu  = W + (bid ? W_QCUR   : W_GCUR);
        const int lane = tid & 63, wid = tid >> 6;
        int carry = 0;
        for (int base = 0; base < 1024; base += 256) {
            const int idx = base + tid;
            int v = (idx < NCELL) ? cnt[idx] : 0;
            int x = v;
            #pragma unroll
            for (int o = 1; o < 64; o <<= 1) { int y = __shfl_up(x, o); if (lane >= o) x += y; }
            if (lane == 63) wp[wid] = x;
            __syncthreads();
            int off = carry, tot = 0;
            #pragma unroll
            for (int k = 0; k < 4; ++k) { tot += wp[k]; if (k < wid) off += wp[k]; }
            if (idx < NCELL) { int ex = off + x - v; st[idx] = ex; cu[idx] = ex; }
            carry += tot;
            __syncthreads();
        }
    }
}

__device__ __forceinline__ void phase_scatter(int gid,
                                              const float* __restrict__ coords,
                                              const float* __restrict__ means,
                                              const float* __restrict__ log_covs,
                                              const float* __restrict__ feats,
                                              int* __restrict__ W) {
    if (gid < N_G) {
        const int c = cell_of(means[gid*3+0], means[gid*3+1], means[gid*3+2]);
        const int slot = atomicAdd(W + W_GCUR + c, 1);
        float4* smi = (float4*)(W + W_SMI);
        float4 m; m.x = means[gid*3+0]; m.y = means[gid*3+1]; m.z = means[gid*3+2]; m.w = 0.f;
        float4 a; a.x = 0.5f * __expf(-log_covs[gid*3+0]);
                  a.y = 0.5f * __expf(-log_covs[gid*3+1]);
                  a.z = 0.5f * __expf(-log_covs[gid*3+2]); a.w = 0.f;
        smi[2*slot]   = m;
        smi[2*slot+1] = a;
        ushort* fgt = (ushort*)(W + W_FGT);
        const float4* f4 = (const float4*)feats;
        #pragma unroll
        for (int k = 0; k < 8; ++k) {
            float4 v = f4[gid*8 + k];
            fgt[(k*4+0)*NPAD + slot] = f2bf(v.x);
            fgt[(k*4+1)*NPAD + slot] = f2bf(v.y);
            fgt[(k*4+2)*NPAD + slot] = f2bf(v.z);
            fgt[(k*4+3)*NPAD + slot] = f2bf(v.w);
        }
    }
    if (gid < M_Q) {
        const int c = cell_of(coords[gid*3+0], coords[gid*3+1], coords[gid*3+2]);
        const int slot = atomicAdd(W + W_QCUR + c, 1);
        W[W_SORTQ + slot] = gid;
        float4 q; q.x = coords[gid*3+0]; q.y = coords[gid*3+1]; q.z = coords[gid*3+2]; q.w = 0.f;
        ((float4*)(W + W_SCRD))[slot] = q;
    }
}

// ---- cooperative prep: zero -> count -> scan -> scatter (128 blocks) ----
__global__ __launch_bounds__(256, 4)
void k_prep(const float* __restrict__ coords, const float* __restrict__ means,
            const float* __restrict__ log_covs, const float* __restrict__ feats,
            int* __restrict__ W)
{
    __shared__ int wp[4];
    cg::grid_group g = cg::this_grid();
    const int tid = threadIdx.x, bid = blockIdx.x, gid = bid * 256 + tid;

    if (gid < 2000) W[W_GCNT + gid] = 0;     // gCnt+qCnt contiguous
    g.sync();
    phase_count(gid, coords, means, W);
    g.sync();
    phase_scan(bid, tid, wp, W);
    g.sync();
    phase_scatter(gid, coords, means, log_covs, feats, W);
}

// ---- fallback prep kernels ----
__global__ __launch_bounds__(256) void k_count(const float* c, const float* m, int* W) {
    phase_count(blockIdx.x * 256 + threadIdx.x, c, m, W);
}
__global__ __launch_bounds__(256) void k_scan(int* W) {
    __shared__ int wp[4];
    phase_scan(blockIdx.x, threadIdx.x, wp, W);
}
__global__ __launch_bounds__(256) void k_scatter(const float* c, const float* m,
                                                 const float* lc, const float* f, int* W) {
    phase_scatter(blockIdx.x * 256 + threadIdx.x, c, m, lc, f, W);
}

// ---- main splash (MFMA; barrier-free chunk loop) ----
__global__ __launch_bounds__(256, 4)
void k_splash(const int* __restrict__ W, float* __restrict__ out)
{
    __shared__ int    ldsIdx[MAXC];     // 1.5 KB
    __shared__ ushort FtT[32][FTP];     // 24.5 KB  bf16 feats, f-major, 0-padded
    __shared__ float4 ldsQ[64];         // 1 KB
    __shared__ int    qList[64];        // 256 B
    __shared__ ushort Wq[64][72];       // 9 KB (144B rows, wave-private)
    // total 36.3 KB -> 4 blocks/CU

    const int cell = blockIdx.x;
    const int tid  = threadIdx.x, lane = tid & 63, wv = tid >> 6;

    const int qStart = W[W_QSTART + cell];
    const int qCnt   = W[W_QCNT   + cell];
    if (qCnt == 0) return;              // uniform exit before any barrier

    // 9 z-spans of the 27-cell neighborhood (scalar bookkeeping)
    const int cx = cell / 100, cyy = (cell / 10) % 10, cz = cell % 10;
    const int z0 = max(cz - 1, 0), z1 = min(cz + 1, GD - 1);
    int sStart[9], sOff[9];
    int T = 0;
    #pragma unroll
    for (int k = 0; k < 9; ++k) {
        const int ax = cx + k / 3 - 1, ay = cyy + k % 3 - 1;
        const bool ok = ((unsigned)ax < (unsigned)GD) && ((unsigned)ay < (unsigned)GD);
        const int cb = (ax * GD + ay) * GD;
        const int jb = ok ? W[W_GSTART + cb + z0] : 0;
        const int je = ok ? (W[W_GSTART + cb + z1] + W[W_GCNT + cb + z1]) : 0;
        sStart[k] = jb; sOff[k] = T;
        T += (je > jb) ? (je - jb) : 0;
    }
    if (T > MAXC) T = MAXC;

    // stage flattened candidate-slot list
    for (int i = tid; i < T; i += 256) {
        int s = 0;
        #pragma unroll
        for (int k = 0; k < 9; ++k) {
            const int hi = (k == 8) ? T : sOff[k + 1];
            if (i >= sOff[k] && i < hi) s = sStart[k] + (i - sOff[k]);
        }
        ldsIdx[i] = s;
    }
    __syncthreads();                    // ldsIdx visible

    const float4* smi4  = (const float4*)(W + W_SMI);
    const float4* scrd4 = (const float4*)(W + W_SCRD);
    const ushort* fgt   = (const ushort*)(W + W_FGT);

    // stage ALL candidates' feats once (bf16, f-major), ZERO-padding cols
    // [T, MAXC) — MFMA B-reads touch up to nkch*64-1 and 0*NaN = NaN.
    {
        const int ia = tid, ib = tid + 256;
        const int idA = (ia < T) ? ldsIdx[ia] : -1;
        const int idB = (ib < T) ? ldsIdx[ib] : -1;
        #pragma unroll 8
        for (int f = 0; f < 32; ++f) {
            FtT[f][ia] = (idA >= 0) ? fgt[f * NPAD + idA] : (ushort)0;
            if (ib < MAXC)
                FtT[f][ib] = (idB >= 0) ? fgt[f * NPAD + idB] : (ushort)0;
        }
    }

    const int nkch = (T + 63) >> 6;

    for (int qb = 0; qb < qCnt; qb += 64) {
        const int qw = min(qCnt - qb, 64);
        __syncthreads();                // FtT staged (1st) / prev epilogue done
        if (tid < 64) {
            const int qi = min(tid, qw - 1);        // clamp: finite dup
            ldsQ[tid]  = scrd4[qStart + qb + qi];
            qList[tid] = W[W_SORTQ + qStart + qb + qi];
        }
        __syncthreads();                // ldsQ/qList visible

        const bool waveActive = (wv * 16) < qw;
        f32x4 acc0 = {0,0,0,0}, acc1 = {0,0,0,0}, acc2 = {0,0,0,0};
        const short ov = ((lane & 15) == 0) ? (short)0x3F80 : (short)0;  // 1.0bf16
        const bf16x8 bones = {ov,ov,ov,ov,ov,ov,ov,ov};

        if (waveActive) {
            // barrier-free: Wq rows wv*16..+15 are written AND read only by
            // wave wv (same-wave ds ordering handled by compiler lgkmcnt).
            for (int c = 0; c < nkch; ++c) {
                const int cb = c << 6;
                const int fi = cb + lane;           // lane = candidate
                const bool kOK = fi < T;
                const int  s   = kOK ? ldsIdx[fi] : 0;
                const float4 gm = smi4[2*s];
                const float4 ga = smi4[2*s+1];
                #pragma unroll
                for (int qq = 0; qq < 16; ++qq) {
                    const int q = wv*16 + qq;
                    const float4 qv = ldsQ[q];      // LDS broadcast
                    const float dx = qv.x - gm.x, dy = qv.y - gm.y, dz = qv.z - gm.z;
                    const float s2 = dx*dx*ga.x + dy*dy*ga.y + dz*dz*ga.z;
                    const float w  = kOK ? __expf(-s2) : 0.f;   // far -> 0
                    Wq[q][lane] = f2bf(w);
                }
                #pragma unroll
                for (int ks = 0; ks < 2; ++ks) {
                    const int k0 = (ks << 5) + ((lane >> 4) << 3);
                    const bf16x8 a  = *(const bf16x8*)&Wq[wv*16 + (lane & 15)][k0];
                    const bf16x8 b0 = *(const bf16x8*)&FtT[(lane & 15)][cb + k0];
                    const bf16x8 b1 = *(const bf16x8*)&FtT[16 + (lane & 15)][cb + k0];
                    acc0 = __builtin_amdgcn_mfma_f32_16x16x32_bf16(a, b0,    acc0, 0, 0, 0);
                    acc1 = __builtin_amdgcn_mfma_f32_16x16x32_bf16(a, b1,    acc1, 0, 0, 0);
                    acc2 = __builtin_amdgcn_mfma_f32_16x16x32_bf16(a, bones, acc2, 0, 0, 0);
                }
            }

            // epilogue: wsum = acc2 col 0; row r=(lane>>4)*4+i is held by
            // lane (lane & 48) -> shfl (no divergence before the shfl).
            const int fl = lane & 15;
            #pragma unroll
            for (int i = 0; i < 4; ++i) {
                const float ws = __shfl(acc2[i], lane & 48);
                const int q = wv*16 + ((lane >> 4) << 2) + i;
                if (q < qw) {
                    const float inv = 1.0f / (ws + EPS);
                    const int qo = qList[q];
                    out[qo*32 + fl]      = acc0[i] * inv;
                    out[qo*32 + 16 + fl] = acc1[i] * inv;
                }
            }
        }
    }
}

extern "C" void kernel_launch(void* const* d_in, const int* in_sizes, int n_in,
                              void* d_out, int out_size, void* d_ws, size_t ws_size,
                              hipStream_t stream)
{
    const float* coords   = (const float*)d_in[0];
    const float* means    = (const float*)d_in[1];
    const float* log_covs = (const float*)d_in[2];
    const float* feats    = (const float*)d_in[3];
    float* out            = (float*)d_out;
    int*   W              = (int*)d_ws;

    void* args[] = { (void*)&coords, (void*)&means, (void*)&log_covs,
                     (void*)&feats,  (void*)&W };
    hipError_t e = hipLaunchCooperativeKernel((const void*)k_prep,
                                              dim3(128), dim3(256),
                                              args, 0, stream);
    if (e != hipSuccess) {
        // deterministic fallback: same phases as separate dispatches
        hipMemsetAsync(W, 0, 2000 * sizeof(int), stream);   // gCnt+qCnt
        hipLaunchKernelGGL(k_count,   dim3(128), dim3(256), 0, stream, coords, means, W);
        hipLaunchKernelGGL(k_scan,    dim3(2),   dim3(256), 0, stream, W);
        hipLaunchKernelGGL(k_scatter, dim3(128), dim3(256), 0, stream, coords, means, log_covs, feats, W);
    }
    hipLaunchKernelGGL(k_splash, dim3(NCELL), dim3(256), 0, stream, W, out);
}

// Round 12
// 114.531 us; speedup vs baseline: 1.4589x; 1.4589x over previous
//
#include <hip/hip_runtime.h>

// SplashEncoding, round 12 = r11 k_splash + r9 separate prep (coop reverted).
// Radius-sum + MFMA (validated r9/r11: absmax 0.031 vs thr 0.086), 10^3 grid.
// r11 lesson: cooperative prep = 56us (128 blocks, 3 grid.syncs, VALUBusy
// 0.2%) vs ~10us for separate kernels -- coop fusion twice-refuted (r6, r11).
// Structure: memset + k_count + k_scan + k_scatter (r9-proven) then k_splash:
// wave-private Wq (barrier-free chunk loop), FtT staged once (zero-padded
// tail cols), wsum via ones-column MFMA accumulator + __shfl.

typedef short bf16x8 __attribute__((ext_vector_type(8)));
typedef float f32x4  __attribute__((ext_vector_type(4)));

constexpr int   M_Q   = 32768;
constexpr int   N_G   = 10000;
constexpr float EPS   = 1e-8f;
constexpr int   GD    = 10;
constexpr int   NCELL = GD * GD * GD;   // 1000
constexpr int   MAXC  = 384;            // candidate cap (observed max ~340)
constexpr int   FTP   = 392;            // FtT col pad: 784B rows, 4-bank stagger
constexpr int   NPAD  = 10240;          // padded slot count for global FgT rows

// ---- d_ws layout (int units) ----
#define W_GCNT   0          // [1000]
#define W_QCNT   1000       // [1000]
#define W_GSTART 2000       // [1000]
#define W_QSTART 3000       // [1000]
#define W_GCUR   4000       // [1000]
#define W_QCUR   5000       // [1000]
#define W_SORTQ  6000       // [32768]
#define W_SMI    38768      // float4[20000]: {mean.xyz,0},{a.xyz,0} per slot
#define W_SCRD   118768     // float4[32768]: sorted query coords
#define W_FGT    249840     // ushort[32][10240]: bf16 feats TRANSPOSED
// end 413680 ints = 1.65 MB

__device__ __forceinline__ int cell_of(float x, float y, float z) {
    int cx = min(max((int)(x * (float)GD), 0), GD - 1);
    int cy = min(max((int)(y * (float)GD), 0), GD - 1);
    int cz = min(max((int)(z * (float)GD), 0), GD - 1);
    return (cx * GD + cy) * GD + cz;
}

__device__ __forceinline__ ushort f2bf(float x) {   // RNE f32->bf16
    union { float f; unsigned u; } v; v.f = x;
    unsigned r = v.u + 0x7FFFu + ((v.u >> 16) & 1u);
    return (ushort)(r >> 16);
}

// ---- A: count per cell (counters pre-zeroed by memset node) ----
__global__ __launch_bounds__(256)
void k_count(const float* __restrict__ coords,
             const float* __restrict__ means,
             int* __restrict__ W)
{
    const int t = blockIdx.x * 256 + threadIdx.x;
    if (t < N_G)
        atomicAdd(W + W_GCNT + cell_of(means[t*3+0], means[t*3+1], means[t*3+2]), 1);
    if (t < M_Q)
        atomicAdd(W + W_QCNT + cell_of(coords[t*3+0], coords[t*3+1], coords[t*3+2]), 1);
}

// ---- B: exclusive scans; block 0 -> gaussians, block 1 -> queries ----
__global__ __launch_bounds__(256)
void k_scan(int* __restrict__ W)
{
    __shared__ int wp[4];
    const int bid = blockIdx.x, tid = threadIdx.x;
    const int* cnt = W + (bid ? W_QCNT   : W_GCNT);
    int*       st  = W + (bid ? W_QSTART : W_GSTART);
    int*       cu  = W + (bid ? W_QCUR   : W_GCUR);
    const int lane = tid & 63, wid = tid >> 6;
    int carry = 0;
    for (int base = 0; base < 1024; base += 256) {
        const int idx = base + tid;
        int v = (idx < NCELL) ? cnt[idx] : 0;
        int x = v;
        #pragma unroll
        for (int o = 1; o < 64; o <<= 1) { int y = __shfl_up(x, o); if (lane >= o) x += y; }
        if (lane == 63) wp[wid] = x;
        __syncthreads();
        int off = carry, tot = 0;
        #pragma unroll
        for (int k = 0; k < 4; ++k) { tot += wp[k]; if (k < wid) off += wp[k]; }
        if (idx < NCELL) { int ex = off + x - v; st[idx] = ex; cu[idx] = ex; }
        carry += tot;
        __syncthreads();
    }
}

// ---- C: scatter into sorted order (geo f32; feats bf16 TRANSPOSED) ----
__global__ __launch_bounds__(256)
void k_scatter(const float* __restrict__ coords,
               const float* __restrict__ means,
               const float* __restrict__ log_covs,
               const float* __restrict__ feats,
               int* __restrict__ W)
{
    const int t = blockIdx.x * 256 + threadIdx.x;
    if (t < N_G) {
        const int c = cell_of(means[t*3+0], means[t*3+1], means[t*3+2]);
        const int slot = atomicAdd(W + W_GCUR + c, 1);
        float4* smi = (float4*)(W + W_SMI);
        float4 m; m.x = means[t*3+0]; m.y = means[t*3+1]; m.z = means[t*3+2]; m.w = 0.f;
        float4 a; a.x = 0.5f * __expf(-log_covs[t*3+0]);
                  a.y = 0.5f * __expf(-log_covs[t*3+1]);
                  a.z = 0.5f * __expf(-log_covs[t*3+2]); a.w = 0.f;
        smi[2*slot]   = m;
        smi[2*slot+1] = a;
        ushort* fgt = (ushort*)(W + W_FGT);
        const float4* f4 = (const float4*)feats;
        #pragma unroll
        for (int k = 0; k < 8; ++k) {
            float4 v = f4[t*8 + k];
            fgt[(k*4+0)*NPAD + slot] = f2bf(v.x);
            fgt[(k*4+1)*NPAD + slot] = f2bf(v.y);
            fgt[(k*4+2)*NPAD + slot] = f2bf(v.z);
            fgt[(k*4+3)*NPAD + slot] = f2bf(v.w);
        }
    }
    if (t < M_Q) {
        const int c = cell_of(coords[t*3+0], coords[t*3+1], coords[t*3+2]);
        const int slot = atomicAdd(W + W_QCUR + c, 1);
        W[W_SORTQ + slot] = t;
        float4 q; q.x = coords[t*3+0]; q.y = coords[t*3+1]; q.z = coords[t*3+2]; q.w = 0.f;
        ((float4*)(W + W_SCRD))[slot] = q;
    }
}

// ---- D: main splash (MFMA; barrier-free chunk loop) — identical to r11 ----
__global__ __launch_bounds__(256, 4)
void k_splash(const int* __restrict__ W, float* __restrict__ out)
{
    __shared__ int    ldsIdx[MAXC];     // 1.5 KB
    __shared__ ushort FtT[32][FTP];     // 24.5 KB  bf16 feats, f-major, 0-padded
    __shared__ float4 ldsQ[64];         // 1 KB
    __shared__ int    qList[64];        // 256 B
    __shared__ ushort Wq[64][72];       // 9 KB (144B rows, wave-private)
    // total 36.3 KB -> 4 blocks/CU

    const int cell = blockIdx.x;
    const int tid  = threadIdx.x, lane = tid & 63, wv = tid >> 6;

    const int qStart = W[W_QSTART + cell];
    const int qCnt   = W[W_QCNT   + cell];
    if (qCnt == 0) return;              // uniform exit before any barrier

    // 9 z-spans of the 27-cell neighborhood (scalar bookkeeping)
    const int cx = cell / 100, cyy = (cell / 10) % 10, cz = cell % 10;
    const int z0 = max(cz - 1, 0), z1 = min(cz + 1, GD - 1);
    int sStart[9], sOff[9];
    int T = 0;
    #pragma unroll
    for (int k = 0; k < 9; ++k) {
        const int ax = cx + k / 3 - 1, ay = cyy + k % 3 - 1;
        const bool ok = ((unsigned)ax < (unsigned)GD) && ((unsigned)ay < (unsigned)GD);
        const int cb = (ax * GD + ay) * GD;
        const int jb = ok ? W[W_GSTART + cb + z0] : 0;
        const int je = ok ? (W[W_GSTART + cb + z1] + W[W_GCNT + cb + z1]) : 0;
        sStart[k] = jb; sOff[k] = T;
        T += (je > jb) ? (je - jb) : 0;
    }
    if (T > MAXC) T = MAXC;

    // stage flattened candidate-slot list
    for (int i = tid; i < T; i += 256) {
        int s = 0;
        #pragma unroll
        for (int k = 0; k < 9; ++k) {
            const int hi = (k == 8) ? T : sOff[k + 1];
            if (i >= sOff[k] && i < hi) s = sStart[k] + (i - sOff[k]);
        }
        ldsIdx[i] = s;
    }
    __syncthreads();                    // ldsIdx visible

    const float4* smi4  = (const float4*)(W + W_SMI);
    const float4* scrd4 = (const float4*)(W + W_SCRD);
    const ushort* fgt   = (const ushort*)(W + W_FGT);

    // stage ALL candidates' feats once (bf16, f-major), ZERO-padding cols
    // [T, MAXC) — MFMA B-reads touch up to nkch*64-1 and 0*NaN = NaN.
    {
        const int ia = tid, ib = tid + 256;
        const int idA = (ia < T) ? ldsIdx[ia] : -1;
        const int idB = (ib < T) ? ldsIdx[ib] : -1;
        #pragma unroll 8
        for (int f = 0; f < 32; ++f) {
            FtT[f][ia] = (idA >= 0) ? fgt[f * NPAD + idA] : (ushort)0;
            if (ib < MAXC)
                FtT[f][ib] = (idB >= 0) ? fgt[f * NPAD + idB] : (ushort)0;
        }
    }

    const int nkch = (T + 63) >> 6;

    for (int qb = 0; qb < qCnt; qb += 64) {
        const int qw = min(qCnt - qb, 64);
        __syncthreads();                // FtT staged (1st) / prev epilogue done
        if (tid < 64) {
            const int qi = min(tid, qw - 1);        // clamp: finite dup
            ldsQ[tid]  = scrd4[qStart + qb + qi];
            qList[tid] = W[W_SORTQ + qStart + qb + qi];
        }
        __syncthreads();                // ldsQ/qList visible

        const bool waveActive = (wv * 16) < qw;
        f32x4 acc0 = {0,0,0,0}, acc1 = {0,0,0,0}, acc2 = {0,0,0,0};
        const short ov = ((lane & 15) == 0) ? (short)0x3F80 : (short)0;  // 1.0bf16
        const bf16x8 bones = {ov,ov,ov,ov,ov,ov,ov,ov};

        if (waveActive) {
            // barrier-free: Wq rows wv*16..+15 are written AND read only by
            // wave wv (same-wave ds ordering handled by compiler lgkmcnt).
            for (int c = 0; c < nkch; ++c) {
                const int cb = c << 6;
                const int fi = cb + lane;           // lane = candidate
                const bool kOK = fi < T;
                const int  s   = kOK ? ldsIdx[fi] : 0;
                const float4 gm = smi4[2*s];
                const float4 ga = smi4[2*s+1];
                #pragma unroll
                for (int qq = 0; qq < 16; ++qq) {
                    const int q = wv*16 + qq;
                    const float4 qv = ldsQ[q];      // LDS broadcast
                    const float dx = qv.x - gm.x, dy = qv.y - gm.y, dz = qv.z - gm.z;
                    const float s2 = dx*dx*ga.x + dy*dy*ga.y + dz*dz*ga.z;
                    const float w  = kOK ? __expf(-s2) : 0.f;   // far -> 0
                    Wq[q][lane] = f2bf(w);
                }
                #pragma unroll
                for (int ks = 0; ks < 2; ++ks) {
                    const int k0 = (ks << 5) + ((lane >> 4) << 3);
                    const bf16x8 a  = *(const bf16x8*)&Wq[wv*16 + (lane & 15)][k0];
                    const bf16x8 b0 = *(const bf16x8*)&FtT[(lane & 15)][cb + k0];
                    const bf16x8 b1 = *(const bf16x8*)&FtT[16 + (lane & 15)][cb + k0];
                    acc0 = __builtin_amdgcn_mfma_f32_16x16x32_bf16(a, b0,    acc0, 0, 0, 0);
                    acc1 = __builtin_amdgcn_mfma_f32_16x16x32_bf16(a, b1,    acc1, 0, 0, 0);
                    acc2 = __builtin_amdgcn_mfma_f32_16x16x32_bf16(a, bones, acc2, 0, 0, 0);
                }
            }

            // epilogue: wsum = acc2 col 0; row r=(lane>>4)*4+i is held by
            // lane (lane & 48) -> shfl (no divergence before the shfl).
            const int fl = lane & 15;
            #pragma unroll
            for (int i = 0; i < 4; ++i) {
                const float ws = __shfl(acc2[i], lane & 48);
                const int q = wv*16 + ((lane >> 4) << 2) + i;
                if (q < qw) {
                    const float inv = 1.0f / (ws + EPS);
                    const int qo = qList[q];
                    out[qo*32 + fl]      = acc0[i] * inv;
                    out[qo*32 + 16 + fl] = acc1[i] * inv;
                }
            }
        }
    }
}

extern "C" void kernel_launch(void* const* d_in, const int* in_sizes, int n_in,
                              void* d_out, int out_size, void* d_ws, size_t ws_size,
                              hipStream_t stream)
{
    const float* coords   = (const float*)d_in[0];
    const float* means    = (const float*)d_in[1];
    const float* log_covs = (const float*)d_in[2];
    const float* feats    = (const float*)d_in[3];
    float* out            = (float*)d_out;
    int*   W              = (int*)d_ws;

    hipMemsetAsync(W, 0, 2000 * sizeof(int), stream);   // gCnt+qCnt

    hipLaunchKernelGGL(k_count,   dim3(128),   dim3(256), 0, stream, coords, means, W);
    hipLaunchKernelGGL(k_scan,    dim3(2),     dim3(256), 0, stream, W);
    hipLaunchKernelGGL(k_scatter, dim3(128),   dim3(256), 0, stream, coords, means, log_covs, feats, W);
    hipLaunchKernelGGL(k_splash,  dim3(NCELL), dim3(256), 0, stream, W, out);
}